// Round 2
// baseline (507.891 us; speedup 1.0000x reference)
//
#include <hip/hip_runtime.h>
#include <hip/hip_bf16.h>
#include <math.h>

#define N_PROTS 2048
#define N_MOLS  16384
#define DIM     768
#define SHIFT   16.0f
#define MARGIN  0.5f

typedef __attribute__((ext_vector_type(8))) short short8;
typedef __attribute__((ext_vector_type(4))) float f32x4;
typedef __attribute__((ext_vector_type(4))) unsigned short us4;
typedef __attribute__((ext_vector_type(8))) unsigned short us8;

__device__ __forceinline__ unsigned short bf16rnd(float x) {
    unsigned int u = __float_as_uint(x);
    u += 0x7fffu + ((u >> 16) & 1u);   // round-to-nearest-even
    return (unsigned short)(u >> 16);
}

__device__ __forceinline__ void gload16(const void* g, void* l) {
    __builtin_amdgcn_global_load_lds(
        (const __attribute__((address_space(1))) unsigned int*)g,
        (__attribute__((address_space(3))) unsigned int*)l, 16, 0, 0);
}

// sigma swizzle: slot permutation that depends on row mod 16 such that
// fragment reads (16 lanes, fixed k-chunk q, rows base+l15) hit each
// 4-bank group exactly twice (2-way = free). bank = (l15&1)*16 + (q^sig)*4.
__device__ __forceinline__ int sig4(int x) { return (x + (x >> 2)) & 3; }

// ws layout:
//  floats [0, 34824): 0..2048 row_sumexp | 2048..18432 col_sumexp |
//                     18432..34816 pos_sim | 34816..34824 scalars
//  then 16B-aligned: protBf (2048*768 bf16, linear), molBf (16384*768 bf16, linear)
#define ACC_FLOATS 34824
#define PROT_BF_OFF_B 139296ull                      // 34824*4, 16B aligned
#define PROT_BF_BYTES (2048ull*768*2)
#define MOL_BF_OFF_B  (PROT_BF_OFF_B + PROT_BF_BYTES)
#define MOL_BF_BYTES  (16384ull*768*2)
#define WS_NEED       (MOL_BF_OFF_B + MOL_BF_BYTES)  // ~28.5 MB

// -------- one-shot fp32 -> bf16 conversion (+ fused ws zeroing) -----------
__global__ __launch_bounds__(256)
void convert_bf16(const float* __restrict__ prot, const float* __restrict__ mol,
                  unsigned short* __restrict__ protBf, unsigned short* __restrict__ molBf,
                  float* __restrict__ wsZero)
{
    const size_t PROT_G = (size_t)N_PROTS * DIM / 8;   // 16B chunks
    size_t t = (size_t)blockIdx.x * 256 + threadIdx.x;
    // fused zeroing of the accumulator region (replaces hipMemsetAsync node)
    if (t < ACC_FLOATS / 4) {
        float4 z = {0.f, 0.f, 0.f, 0.f};
        ((float4*)wsZero)[t] = z;
    }
    const float* src;
    unsigned short* dst;
    if (t < PROT_G) { src = prot + t * 8; dst = protBf + t * 8; }
    else            { size_t u = t - PROT_G; src = mol + u * 8; dst = molBf + u * 8; }
    float4 v0 = ((const float4*)src)[0];
    float4 v1 = ((const float4*)src)[1];
    us8 o;
    o[0] = bf16rnd(v0.x); o[1] = bf16rnd(v0.y); o[2] = bf16rnd(v0.z); o[3] = bf16rnd(v0.w);
    o[4] = bf16rnd(v1.x); o[5] = bf16rnd(v1.y); o[6] = bf16rnd(v1.z); o[7] = bf16rnd(v1.w);
    *(us8*)dst = o;
}

// ---- bf16 GEMM v3: persistent tile-pairs, 256x256, BK=32, 4-slot counted pipe ----
// Grid = 256 (exactly 1 block/CU). Each block computes TWO 256x256 C-tiles
// sharing the same B panel (by = byp and byp+4), as ONE seamless 48-phase
// pipeline: staging for C-tile 2 is issued during C-tile 1's last phases, and
// the C-tile-1 epilogue overlaps those in-flight loads. One s_barrier + one
// counted s_waitcnt vmcnt(8) per phase; vmcnt never drains to 0 in the loop.
// Swizzle: LDS slot s of row r holds global chunk s ^ sig4(r&15); reads use
// slot q ^ sig4(l15) -> 2-way bank aliasing only (free).
__global__ __launch_bounds__(512, 2)
void sim_pass_bf16_v3(const unsigned short* __restrict__ protBf,
                      const unsigned short* __restrict__ molBf,
                      const float* __restrict__ scale_p,
                      float* __restrict__ row_se, float* __restrict__ col_se,
                      float* __restrict__ pos_sim, float* __restrict__ scalars)
{
    __shared__ unsigned short As[4][256][32];   // 64 KB
    __shared__ unsigned short Bs[4][256][32];   // 64 KB
    __shared__ float redBuf[8];

    const int tid = threadIdx.x;
    // XCD-aware: bid%8 = hardware XCD round-robin. Each XCD owns an 8-wide
    // bx band (2048 cols of B = 3 MB, L2-resident, shared by its 32 blocks).
    const int bid = blockIdx.x;                // 0..255
    const int xcd = bid & 7;
    const int s8  = bid >> 3;                  // 0..31
    const int bx  = xcd * 8 + (s8 & 7);        // 0..63 (col tile)
    const int byp = s8 >> 3;                   // 0..3  (row tile pair: byp, byp+4)
    const int rowBase0 = byp * 256;
    const int colBase  = bx * 256;

    const int wave = tid >> 6;
    const int lane = tid & 63;
    const int wm = wave >> 2;                  // 0..1  -> 128-row half
    const int wn = wave & 3;                   // 0..3  -> 64-col slice
    const int l15 = lane & 15;
    const int q   = lane >> 4;

    // ---- staging addresses (per-thread, pre-swizzled global source) ----
    const int rsub = lane >> 2;                // 0..15 row within 16-row group
    const int cs   = lane & 3;                 // LDS chunk slot
    const int csrc = (cs ^ sig4(rsub)) << 3;   // halfword offset of source chunk
    const unsigned short* aP =
        protBf + (size_t)(rowBase0 + wave * 32 + rsub) * DIM + csrc;
    const unsigned short* bP =
        molBf  + (size_t)(colBase  + wave * 32 + rsub) * DIM + csrc;
    const size_t A_CT = (size_t)1024 * DIM;    // ct1 row offset (+4 tiles)

#define STAGE_A(sl, ptr) do { \
    gload16((ptr),                     &As[sl][wave * 32][0]);      \
    gload16((ptr) + (size_t)16 * DIM,  &As[sl][wave * 32 + 16][0]); \
} while (0)
#define STAGE_B(sl, ptr) do { \
    gload16((ptr),                     &Bs[sl][wave * 32][0]);      \
    gload16((ptr) + (size_t)16 * DIM,  &Bs[sl][wave * 32 + 16][0]); \
} while (0)

    f32x4 acc[8][4];
#pragma unroll
    for (int i = 0; i < 8; ++i)
#pragma unroll
        for (int j = 0; j < 4; ++j) acc[i][j] = (f32x4){0.f, 0.f, 0.f, 0.f};

    // ---- prologue: stage tiles 0,1,2 (ct0, kt 0..2; 12 loads/thread) ----
    STAGE_A(0, aP);      STAGE_B(0, bP);
    STAGE_A(1, aP + 32); STAGE_B(1, bP + 32);
    STAGE_A(2, aP + 64); STAGE_B(2, bP + 64);

    // fragment read geometry
    const int fArow = wm * 128 + l15;          // + mi*16
    const int fBrow = wn * 64 + l15;           // + ni*16
    const int fsw   = (q ^ sig4(l15)) << 3;    // halfword offset (16B aligned)

    const float scale = scale_p[0];
    float csum[4] = {0.f, 0.f, 0.f, 0.f};
    float rl = 0.f;

// one pipeline phase: wait(counted) -> barrier -> ds_read || stage -> MFMA
#define TILE_BODY(sl, pf, aPt, bPt) do {                                      \
    asm volatile("s_waitcnt vmcnt(8)" ::: "memory");                          \
    __builtin_amdgcn_s_barrier();                                             \
    short8 aF[4], bF[4];                                                      \
    _Pragma("unroll")                                                         \
    for (int ni = 0; ni < 4; ++ni)                                            \
        bF[ni] = *(const short8*)&Bs[sl][fBrow + ni * 16][fsw];               \
    _Pragma("unroll")                                                         \
    for (int mi = 0; mi < 4; ++mi)                                            \
        aF[mi] = *(const short8*)&As[sl][fArow + mi * 16][fsw];               \
    STAGE_A(pf, aPt);                                                         \
    __builtin_amdgcn_s_setprio(1);                                            \
    _Pragma("unroll")                                                         \
    for (int mi = 0; mi < 4; ++mi)                                            \
        _Pragma("unroll")                                                     \
        for (int ni = 0; ni < 4; ++ni)                                        \
            acc[mi][ni] = __builtin_amdgcn_mfma_f32_16x16x32_bf16(            \
                aF[mi], bF[ni], acc[mi][ni], 0, 0, 0);                        \
    __builtin_amdgcn_s_setprio(0);                                            \
    _Pragma("unroll")                                                         \
    for (int mi = 0; mi < 4; ++mi)                                            \
        aF[mi] = *(const short8*)&As[sl][fArow + 64 + mi * 16][fsw];          \
    STAGE_B(pf, bPt);                                                         \
    __builtin_amdgcn_s_setprio(1);                                            \
    _Pragma("unroll")                                                         \
    for (int mi = 0; mi < 4; ++mi)                                            \
        _Pragma("unroll")                                                     \
        for (int ni = 0; ni < 4; ++ni)                                        \
            acc[4 + mi][ni] = __builtin_amdgcn_mfma_f32_16x16x32_bf16(        \
                aF[mi], bF[ni], acc[4 + mi][ni], 0, 0, 0);                    \
    __builtin_amdgcn_s_setprio(0);                                            \
} while (0)

// epilogue for one C-tile: exp-sum rows/cols, relu-sum, pos_sim diagonal
#define EPILOG(rowBaseX) do {                                                 \
    _Pragma("unroll")                                                         \
    for (int mi = 0; mi < 8; ++mi) {                                          \
        float rs[4] = {0.f, 0.f, 0.f, 0.f};                                   \
        _Pragma("unroll")                                                     \
        for (int ni = 0; ni < 4; ++ni) {                                      \
            _Pragma("unroll")                                                 \
            for (int r = 0; r < 4; ++r) {                                     \
                float sim = acc[mi][ni][r] * scale;                           \
                float e = __expf(sim - SHIFT);                                \
                rs[r] += e;                                                   \
                csum[ni] += e;                                                \
                rl += fmaxf(sim, 0.f);                                        \
                int rg = (rowBaseX) + wm * 128 + mi * 16 + q * 4 + r;         \
                int cg = colBase + wn * 64 + ni * 16 + l15;                   \
                if ((cg >> 3) == rg) pos_sim[cg] = sim;                       \
            }                                                                 \
        }                                                                     \
        _Pragma("unroll")                                                     \
        for (int r = 0; r < 4; ++r) {                                         \
            float v = rs[r];                                                  \
            v += __shfl_xor(v, 1); v += __shfl_xor(v, 2);                     \
            v += __shfl_xor(v, 4); v += __shfl_xor(v, 8);                     \
            if (l15 == 0)                                                     \
                atomicAdd(&row_se[(rowBaseX) + wm * 128 + mi * 16 + q * 4 + r], v); \
        }                                                                     \
    }                                                                         \
} while (0)

    // ---- C-tile 0: phases 0..23 (staging runs ahead into ct1) ----
#pragma unroll 1
    for (int t = 0; t < 24; ++t) {
        const int u   = t + 3;                       // staged tile index 3..26
        const int ctU = (u >= 24);
        const int ktU = u - (ctU ? 24 : 0);
        const unsigned short* aPt = aP + (ctU ? A_CT : 0) + (size_t)ktU * 32;
        const unsigned short* bPt = bP + (size_t)ktU * 32;
        TILE_BODY(t & 3, u & 3, aPt, bPt);
    }

    // C-tile 0 epilogue overlaps in-flight ct1 staging (no barrier here)
    EPILOG(rowBase0);
#pragma unroll
    for (int i = 0; i < 8; ++i)
#pragma unroll
        for (int j = 0; j < 4; ++j) acc[i][j] = (f32x4){0.f, 0.f, 0.f, 0.f};

    // ---- C-tile 1: phases 24..47 (tail phases re-stage dead slots) ----
#pragma unroll 1
    for (int t = 24; t < 48; ++t) {
        const int u  = t + 3;                        // 27..50
        const int uu = (u < 48) ? u : (u - 8);       // dummy: re-stage done tiles
        const int ktU = uu - 24;
        const unsigned short* aPt = aP + A_CT + (size_t)ktU * 32;
        const unsigned short* bPt = bP + (size_t)ktU * 32;
        TILE_BODY(t & 3, u & 3, aPt, bPt);
    }
    asm volatile("s_waitcnt vmcnt(0)" ::: "memory");   // retire dummy stages

    EPILOG(rowBase0 + 1024);

#undef STAGE_A
#undef STAGE_B
#undef TILE_BODY
#undef EPILOG

    // column sums (accumulated across both C-tiles) + relu-sum reduction
#pragma unroll
    for (int ni = 0; ni < 4; ++ni) {
        float v = csum[ni];
        v += __shfl_xor(v, 16); v += __shfl_xor(v, 32);
        if (q == 0)
            atomicAdd(&col_se[colBase + wn * 64 + ni * 16 + l15], v);
    }
#pragma unroll
    for (int m = 1; m < 64; m <<= 1) rl += __shfl_xor(rl, m);
    if (lane == 0) redBuf[wave] = rl;
    __syncthreads();
    if (tid == 0) {
        float sv = 0.f;
#pragma unroll
        for (int w = 0; w < 8; ++w) sv += redBuf[w];
        atomicAdd(&scalars[0], sv);
    }
}

// ---------------- fallback: fp32-staging GEMM (R1 kernel, known-good) --------
__global__ __launch_bounds__(256, 2)
void sim_pass(const float* __restrict__ prot, const float* __restrict__ mol,
              const float* __restrict__ scale_p,
              float* __restrict__ row_se, float* __restrict__ col_se,
              float* __restrict__ pos_sim, float* __restrict__ scalars)
{
    __shared__ unsigned short As[128][32];
    __shared__ unsigned short Bs[128][32];
    __shared__ float redBuf[4];

    const int tid = threadIdx.x;
    const int rowBase = blockIdx.y * 128;
    const int colBase = blockIdx.x * 128;
    const int wave = tid >> 6;
    const int lane = tid & 63;
    const int wr = (wave >> 1) * 64;
    const int wc = (wave & 1) * 64;
    const int l15 = lane & 15;
    const int q   = lane >> 4;

    f32x4 acc[4][4];
#pragma unroll
    for (int i = 0; i < 4; ++i)
#pragma unroll
        for (int j = 0; j < 4; ++j) acc[i][j] = (f32x4){0.f, 0.f, 0.f, 0.f};

    const float* aBase = prot + (size_t)rowBase * DIM;
    const float* bBase = mol  + (size_t)colBase * DIM;
    float4 aReg[4], bReg[4];
#pragma unroll
    for (int i = 0; i < 4; ++i) {
        int f = tid + 256 * i;
        int row = f >> 3, c4 = f & 7;
        aReg[i] = *(const float4*)(aBase + (size_t)row * DIM + (c4 << 2));
        bReg[i] = *(const float4*)(bBase + (size_t)row * DIM + (c4 << 2));
    }
#pragma unroll 1
    for (int s = 0; s < DIM / 32; ++s) {
#pragma unroll
        for (int i = 0; i < 4; ++i) {
            int f = tid + 256 * i;
            int row = f >> 3, c4 = f & 7;
            us4 av, bv;
            av.x = bf16rnd(aReg[i].x); av.y = bf16rnd(aReg[i].y);
            av.z = bf16rnd(aReg[i].z); av.w = bf16rnd(aReg[i].w);
            bv.x = bf16rnd(bReg[i].x); bv.y = bf16rnd(bReg[i].y);
            bv.z = bf16rnd(bReg[i].z); bv.w = bf16rnd(bReg[i].w);
            *(us4*)&As[row][c4 << 2] = av;
            *(us4*)&Bs[row][c4 << 2] = bv;
        }
        __syncthreads();
        if (s + 1 < DIM / 32) {
            int k0 = (s + 1) * 32;
#pragma unroll
            for (int i = 0; i < 4; ++i) {
                int f = tid + 256 * i;
                int row = f >> 3, c4 = f & 7;
                aReg[i] = *(const float4*)(aBase + (size_t)row * DIM + k0 + (c4 << 2));
                bReg[i] = *(const float4*)(bBase + (size_t)row * DIM + k0 + (c4 << 2));
            }
        }
        short8 aF[4], bF[4];
#pragma unroll
        for (int mi = 0; mi < 4; ++mi) aF[mi] = *(const short8*)&As[wr + mi * 16 + l15][q * 8];
#pragma unroll
        for (int ni = 0; ni < 4; ++ni) bF[ni] = *(const short8*)&Bs[wc + ni * 16 + l15][q * 8];
#pragma unroll
        for (int mi = 0; mi < 4; ++mi)
#pragma unroll
            for (int ni = 0; ni < 4; ++ni)
                acc[mi][ni] = __builtin_amdgcn_mfma_f32_16x16x32_bf16(aF[mi], bF[ni], acc[mi][ni], 0, 0, 0);
        __syncthreads();
    }

    const float scale = scale_p[0];
    float rsum[4][4];
    float csum[4] = {0.f, 0.f, 0.f, 0.f};
    float rl = 0.f;
#pragma unroll
    for (int mi = 0; mi < 4; ++mi)
#pragma unroll
        for (int r = 0; r < 4; ++r) rsum[mi][r] = 0.f;
#pragma unroll
    for (int mi = 0; mi < 4; ++mi) {
#pragma unroll
        for (int ni = 0; ni < 4; ++ni) {
#pragma unroll
            for (int r = 0; r < 4; ++r) {
                float sim = acc[mi][ni][r] * scale;
                float e = __expf(sim - SHIFT);
                rsum[mi][r] += e;
                csum[ni] += e;
                rl += fmaxf(sim, 0.f);
                int rg = rowBase + wr + mi * 16 + q * 4 + r;
                int cg = colBase + wc + ni * 16 + l15;
                if ((cg >> 3) == rg) pos_sim[cg] = sim;
            }
        }
    }
#pragma unroll
    for (int mi = 0; mi < 4; ++mi) {
#pragma unroll
        for (int r = 0; r < 4; ++r) {
            float v = rsum[mi][r];
            v += __shfl_xor(v, 1); v += __shfl_xor(v, 2);
            v += __shfl_xor(v, 4); v += __shfl_xor(v, 8);
            if (l15 == 0)
                atomicAdd(&row_se[rowBase + wr + mi * 16 + q * 4 + r], v);
        }
    }
#pragma unroll
    for (int ni = 0; ni < 4; ++ni) {
        float v = csum[ni];
        v += __shfl_xor(v, 16); v += __shfl_xor(v, 32);
        if (q == 0)
            atomicAdd(&col_se[colBase + wc + ni * 16 + l15], v);
    }
#pragma unroll
    for (int m = 1; m < 64; m <<= 1) rl += __shfl_xor(rl, m);
    if (lane == 0) redBuf[wave] = rl;
    __syncthreads();
    if (tid == 0)
        atomicAdd(&scalars[0], redBuf[0] + redBuf[1] + redBuf[2] + redBuf[3]);
}

// --------- finalize: single block, block-local reduction, no atomics ---------
__global__ __launch_bounds__(256)
void finalize_all(const float* __restrict__ row_se, const float* __restrict__ col_se,
                  const float* __restrict__ pos_sim, const float* __restrict__ pic50,
                  const float* __restrict__ scalars, float* __restrict__ out)
{
    const int tid = threadIdx.x;
    float m2p = 0.f, p2m = 0.f, rank = 0.f, prelu = 0.f;

    for (int j = tid; j < N_MOLS; j += 256)
        m2p += SHIFT + __logf(col_se[j]) - pos_sim[j];

    for (int i = tid; i < N_PROTS; i += 256) {
        const int j0 = i << 3;
        float s[8], pc[8], pr[8];
#pragma unroll
        for (int p = 0; p < 8; ++p) {
            s[p]  = pos_sim[j0 + p];
            pr[p] = pic50[(size_t)i * N_MOLS + j0 + p];
            float x = (pr[p] - 2.0f) * 0.125f;
            pc[p] = fminf(fmaxf(x, 0.f), 1.f);
            prelu += fmaxf(s[p], 0.f);
        }
        float wsum = 1e-8f;
#pragma unroll
        for (int p = 0; p < 8; ++p) wsum += pc[p];
        float lse = SHIFT + __logf(row_se[i]);
        float accp = 0.f;
#pragma unroll
        for (int p = 0; p < 8; ++p) accp += pc[p] * (lse - s[p]);
        p2m += accp / wsum;
#pragma unroll
        for (int a = 0; a < 8; ++a)
#pragma unroll
            for (int b = a + 1; b < 8; ++b) {
                float dp = pr[a] - pr[b];
                float ds = s[a] - s[b];
                float v = (dp > 0.f) ? fmaxf(MARGIN - ds, 0.f)
                        : ((dp < 0.f) ? fmaxf(MARGIN + ds, 0.f) : 0.f);
                rank += v;
            }
    }

#pragma unroll
    for (int m = 1; m < 64; m <<= 1) {
        m2p   += __shfl_xor(m2p, m);
        p2m   += __shfl_xor(p2m, m);
        rank  += __shfl_xor(rank, m);
        prelu += __shfl_xor(prelu, m);
    }
    __shared__ float rbuf[4][4];
    const int wave = tid >> 6, lane = tid & 63;
    if (lane == 0) { rbuf[wave][0] = m2p; rbuf[wave][1] = p2m;
                     rbuf[wave][2] = rank; rbuf[wave][3] = prelu; }
    __syncthreads();
    if (tid == 0) {
        float a = 0, b = 0, c = 0, d = 0;
        for (int w = 0; w < 4; ++w) { a += rbuf[w][0]; b += rbuf[w][1];
                                      c += rbuf[w][2]; d += rbuf[w][3]; }
        float relu_neg = scalars[0] - d;
        float p2mv  = b / (float)N_PROTS;
        float m2pv  = a / (float)N_MOLS;
        float rankv = c / ((float)N_PROTS * 28.0f);
        float negv  = relu_neg / ((float)N_PROTS * (float)N_MOLS);
        out[0] = p2mv + m2pv + 0.5f * rankv + 0.1f * negv;
        out[1] = p2mv;
        out[2] = m2pv;
        out[3] = rankv;
        out[4] = negv;
    }
}

extern "C" void kernel_launch(void* const* d_in, const int* in_sizes, int n_in,
                              void* d_out, int out_size, void* d_ws, size_t ws_size,
                              hipStream_t stream) {
    const float* prot   = (const float*)d_in[0];
    const float* mol    = (const float*)d_in[1];
    const float* pic50  = (const float*)d_in[3];
    const float* lscale = (const float*)d_in[4];

    float* ws      = (float*)d_ws;
    float* row_se  = ws;
    float* col_se  = ws + 2048;
    float* pos_sim = ws + 2048 + 16384;
    float* scalars = ws + 2048 + 16384 + 16384;

    if (ws_size >= WS_NEED) {
        unsigned short* protBf = (unsigned short*)((char*)d_ws + PROT_BF_OFF_B);
        unsigned short* molBf  = (unsigned short*)((char*)d_ws + MOL_BF_OFF_B);
        size_t groups = ((size_t)N_PROTS + N_MOLS) * DIM / 8;   // 1,769,472
        convert_bf16<<<(unsigned)(groups / 256), 256, 0, stream>>>(prot, mol, protBf, molBf, ws);
        sim_pass_bf16_v3<<<256, 512, 0, stream>>>(protBf, molBf, lscale, row_se, col_se, pos_sim, scalars);
    } else {
        hipMemsetAsync(d_ws, 0, (size_t)ACC_FLOATS * sizeof(float), stream);
        dim3 grid(N_MOLS / 128, N_PROTS / 128);
        sim_pass<<<grid, 256, 0, stream>>>(prot, mol, lscale, row_se, col_se, pos_sim, scalars);
    }
    finalize_all<<<1, 256, 0, stream>>>(row_se, col_se, pos_sim, pic50, scalars, (float*)d_out);
}

// Round 3
// 376.831 us; speedup vs baseline: 1.3478x; 1.3478x over previous
//
#include <hip/hip_runtime.h>
#include <hip/hip_bf16.h>
#include <math.h>

#define N_PROTS 2048
#define N_MOLS  16384
#define DIM     768
#define SHIFT   16.0f
#define MARGIN  0.5f

typedef __attribute__((ext_vector_type(8))) short short8;
typedef __attribute__((ext_vector_type(4))) float f32x4;
typedef __attribute__((ext_vector_type(4))) unsigned short us4;
typedef __attribute__((ext_vector_type(8))) unsigned short us8;

__device__ __forceinline__ unsigned short bf16rnd(float x) {
    unsigned int u = __float_as_uint(x);
    u += 0x7fffu + ((u >> 16) & 1u);   // round-to-nearest-even
    return (unsigned short)(u >> 16);
}

__device__ __forceinline__ void gload16(const void* g, void* l) {
    __builtin_amdgcn_global_load_lds(
        (const __attribute__((address_space(1))) unsigned int*)g,
        (__attribute__((address_space(3))) unsigned int*)l, 16, 0, 0);
}

// slot permutation (row mod 16 dependent). Read pattern lands 16 lanes on 8
// distinct 16B slots, 2 rows each -> 2-way bank aliasing (free, m136).
__device__ __forceinline__ int sig4(int x) { return (x + (x >> 2)) & 3; }

// ws layout:
//  floats [0, 34824): 0..2048 row_sumexp | 2048..18432 col_sumexp |
//                     18432..34816 pos_sim | 34816..34824 scalars
//                     (scalars[7] = finalize ticket)
//  then 16B-aligned: protBf (2048*768 bf16), molBf (16384*768 bf16)
#define ACC_FLOATS 34824
#define PROT_BF_OFF_B 139296ull                      // 34824*4, 16B aligned
#define PROT_BF_BYTES (2048ull*768*2)
#define MOL_BF_OFF_B  (PROT_BF_OFF_B + PROT_BF_BYTES)
#define MOL_BF_BYTES  (16384ull*768*2)
#define WS_NEED       (MOL_BF_OFF_B + MOL_BF_BYTES)  // ~28.5 MB

// -------- one-shot fp32 -> bf16 conversion (+ fused ws zeroing) -----------
__global__ __launch_bounds__(256)
void convert_bf16(const float* __restrict__ prot, const float* __restrict__ mol,
                  unsigned short* __restrict__ protBf, unsigned short* __restrict__ molBf,
                  float* __restrict__ wsZero)
{
    const size_t PROT_G = (size_t)N_PROTS * DIM / 8;   // 16B chunks
    size_t t = (size_t)blockIdx.x * 256 + threadIdx.x;
    if (t < (ACC_FLOATS + 3) / 4) {
        float4 z = {0.f, 0.f, 0.f, 0.f};
        ((float4*)wsZero)[t] = z;
    }
    const float* src;
    unsigned short* dst;
    if (t < PROT_G) { src = prot + t * 8; dst = protBf + t * 8; }
    else            { size_t u = t - PROT_G; src = mol + u * 8; dst = molBf + u * 8; }
    float4 v0 = ((const float4*)src)[0];
    float4 v1 = ((const float4*)src)[1];
    us8 o;
    o[0] = bf16rnd(v0.x); o[1] = bf16rnd(v0.y); o[2] = bf16rnd(v0.z); o[3] = bf16rnd(v0.w);
    o[4] = bf16rnd(v1.x); o[5] = bf16rnd(v1.y); o[6] = bf16rnd(v1.z); o[7] = bf16rnd(v1.w);
    *(us8*)dst = o;
}

// ---- bf16 GEMM v4: 256x256 tile, 8 waves, BK=32, 4-slot counted-vmcnt pipe ----
// = v2 structure with the launch_bounds register-cap bug FIXED:
// no min-occupancy arg -> compiler keeps acc[8][4] (128 f32) + fragments in
// the unified VGPR/AGPR file instead of spilling to scratch (v2/v3 showed
// VGPR_Count=128 with 21-146 MB of scratch WRITE_SIZE). LDS (128 KB) pins us
// to 1 block/CU anyway, so the cap bought nothing.
// Pipeline: tile t in slot t&3; during tile t stage tile t+3 into slot
// (t+3)&3 (slot of t-1, fully read before this tile's barrier). One counted
// s_waitcnt vmcnt(8) + one s_barrier per tile; vmcnt never drains in-loop.
__global__ __launch_bounds__(512)
void sim_pass_bf16_v4(const unsigned short* __restrict__ protBf,
                      const unsigned short* __restrict__ molBf,
                      const float* __restrict__ scale_p,
                      float* __restrict__ row_se, float* __restrict__ col_se,
                      float* __restrict__ pos_sim, float* __restrict__ scalars)
{
    __shared__ unsigned short As[4][256][32];   // 64 KB
    __shared__ unsigned short Bs[4][256][32];   // 64 KB
    __shared__ float redBuf[8];

    const int tid = threadIdx.x;
    // XCD-aware: bid%8 = XCD round-robin; each XCD owns an 8-wide bx band.
    const int bid  = blockIdx.x;
    const int xcd  = bid & 7;
    const int sl8  = bid >> 3;                 // 0..63
    const int bx   = xcd * 8 + (sl8 & 7);      // 0..63  (col tile)
    const int by   = sl8 >> 3;                 // 0..7   (row tile)
    const int rowBase = by * 256;
    const int colBase = bx * 256;

    const int wave = tid >> 6;
    const int lane = tid & 63;
    const int wm = wave >> 2;                  // 0..1  -> 128-row half
    const int wn = wave & 3;                   // 0..3  -> 64-col slice
    const int l15 = lane & 15;
    const int q   = lane >> 4;

    // ---- staging addresses (per-thread, pre-swizzled global source) ----
    const int rsub = lane >> 2;                // 0..15 row within 16-row group
    const int cs   = lane & 3;                 // LDS chunk slot
    const int csrc = (cs ^ sig4(rsub)) << 3;   // halfword offset of source chunk
    const unsigned short* aP =
        protBf + (size_t)(rowBase + wave * 32 + rsub) * DIM + csrc;
    const unsigned short* bP =
        molBf  + (size_t)(colBase + wave * 32 + rsub) * DIM + csrc;

#define STAGE_A(sl, ptr) do { \
    gload16((ptr),                     &As[sl][wave * 32][0]);      \
    gload16((ptr) + (size_t)16 * DIM,  &As[sl][wave * 32 + 16][0]); \
} while (0)
#define STAGE_B(sl, ptr) do { \
    gload16((ptr),                     &Bs[sl][wave * 32][0]);      \
    gload16((ptr) + (size_t)16 * DIM,  &Bs[sl][wave * 32 + 16][0]); \
} while (0)

    f32x4 acc[8][4];
#pragma unroll
    for (int i = 0; i < 8; ++i)
#pragma unroll
        for (int j = 0; j < 4; ++j) acc[i][j] = (f32x4){0.f, 0.f, 0.f, 0.f};

    // ---- prologue: stage tiles 0,1,2 (12 loads/thread) ----
    STAGE_A(0, aP);      STAGE_B(0, bP);
    STAGE_A(1, aP + 32); STAGE_B(1, bP + 32);
    STAGE_A(2, aP + 64); STAGE_B(2, bP + 64);

    // fragment read geometry
    const int fArow = wm * 128 + l15;          // + mi*16
    const int fBrow = wn * 64 + l15;           // + ni*16
    const int fsw   = (q ^ sig4(l15)) << 3;    // halfword offset (16B aligned)

#pragma unroll 1
    for (int t = 0; t < 24; ++t) {
        const int sl = t & 3;
        const int pf = (t + 3) & 3;
        const int kt = (t < 21) ? (t + 3) : (t - 5);   // tail: dummy re-stage
        const unsigned short* aPt = aP + (size_t)kt * 32;
        const unsigned short* bPt = bP + (size_t)kt * 32;

        // counted vmcnt: tiles t+1,t+2 (8 loads/thread) stay in flight
        asm volatile("s_waitcnt vmcnt(8)" ::: "memory");
        __builtin_amdgcn_s_barrier();
        __builtin_amdgcn_sched_barrier(0);     // keep ds_reads below barrier

        short8 aF[4], bF[4];
#pragma unroll
        for (int ni = 0; ni < 4; ++ni)
            bF[ni] = *(const short8*)&Bs[sl][fBrow + ni * 16][fsw];
#pragma unroll
        for (int mi = 0; mi < 4; ++mi)
            aF[mi] = *(const short8*)&As[sl][fArow + mi * 16][fsw];
        STAGE_A(pf, aPt);
        __builtin_amdgcn_s_setprio(1);
#pragma unroll
        for (int mi = 0; mi < 4; ++mi)
#pragma unroll
            for (int ni = 0; ni < 4; ++ni)
                acc[mi][ni] = __builtin_amdgcn_mfma_f32_16x16x32_bf16(
                    aF[mi], bF[ni], acc[mi][ni], 0, 0, 0);
        __builtin_amdgcn_s_setprio(0);

#pragma unroll
        for (int mi = 0; mi < 4; ++mi)
            aF[mi] = *(const short8*)&As[sl][fArow + 64 + mi * 16][fsw];
        STAGE_B(pf, bPt);
        __builtin_amdgcn_s_setprio(1);
#pragma unroll
        for (int mi = 0; mi < 4; ++mi)
#pragma unroll
            for (int ni = 0; ni < 4; ++ni)
                acc[4 + mi][ni] = __builtin_amdgcn_mfma_f32_16x16x32_bf16(
                    aF[mi], bF[ni], acc[4 + mi][ni], 0, 0, 0);
        __builtin_amdgcn_s_setprio(0);
    }
    asm volatile("s_waitcnt vmcnt(0)" ::: "memory");   // retire dummy stages
#undef STAGE_A
#undef STAGE_B

    // ---------------- epilogue ----------------
    const float scale = scale_p[0];
    float csum[4] = {0.f, 0.f, 0.f, 0.f};
    float rl = 0.f;
#pragma unroll
    for (int mi = 0; mi < 8; ++mi) {
        float rs[4] = {0.f, 0.f, 0.f, 0.f};
#pragma unroll
        for (int ni = 0; ni < 4; ++ni) {
#pragma unroll
            for (int r = 0; r < 4; ++r) {
                float sim = acc[mi][ni][r] * scale;
                float e = __expf(sim - SHIFT);
                rs[r] += e;
                csum[ni] += e;
                rl += fmaxf(sim, 0.f);
                int rg = rowBase + wm * 128 + mi * 16 + q * 4 + r;
                int cg = colBase + wn * 64 + ni * 16 + l15;
                if ((cg >> 3) == rg) pos_sim[cg] = sim;   // unique writer
            }
        }
#pragma unroll
        for (int r = 0; r < 4; ++r) {
            float v = rs[r];
            v += __shfl_xor(v, 1); v += __shfl_xor(v, 2);
            v += __shfl_xor(v, 4); v += __shfl_xor(v, 8);
            if (l15 == 0)
                atomicAdd(&row_se[rowBase + wm * 128 + mi * 16 + q * 4 + r], v);
        }
    }
#pragma unroll
    for (int ni = 0; ni < 4; ++ni) {
        float v = csum[ni];
        v += __shfl_xor(v, 16); v += __shfl_xor(v, 32);
        if (q == 0)
            atomicAdd(&col_se[colBase + wn * 64 + ni * 16 + l15], v);
    }
#pragma unroll
    for (int m = 1; m < 64; m <<= 1) rl += __shfl_xor(rl, m);
    if (lane == 0) redBuf[wave] = rl;
    __syncthreads();
    if (tid == 0) {
        float sv = 0.f;
#pragma unroll
        for (int w = 0; w < 8; ++w) sv += redBuf[w];
        atomicAdd(&scalars[0], sv);
    }
}

// ---------------- fallback: fp32-staging GEMM (known-good) --------
__global__ __launch_bounds__(256, 2)
void sim_pass(const float* __restrict__ prot, const float* __restrict__ mol,
              const float* __restrict__ scale_p,
              float* __restrict__ row_se, float* __restrict__ col_se,
              float* __restrict__ pos_sim, float* __restrict__ scalars)
{
    __shared__ unsigned short As[128][32];
    __shared__ unsigned short Bs[128][32];
    __shared__ float redBuf[4];

    const int tid = threadIdx.x;
    const int rowBase = blockIdx.y * 128;
    const int colBase = blockIdx.x * 128;
    const int wave = tid >> 6;
    const int lane = tid & 63;
    const int wr = (wave >> 1) * 64;
    const int wc = (wave & 1) * 64;
    const int l15 = lane & 15;
    const int q   = lane >> 4;

    f32x4 acc[4][4];
#pragma unroll
    for (int i = 0; i < 4; ++i)
#pragma unroll
        for (int j = 0; j < 4; ++j) acc[i][j] = (f32x4){0.f, 0.f, 0.f, 0.f};

    const float* aBase = prot + (size_t)rowBase * DIM;
    const float* bBase = mol  + (size_t)colBase * DIM;
    float4 aReg[4], bReg[4];
#pragma unroll
    for (int i = 0; i < 4; ++i) {
        int f = tid + 256 * i;
        int row = f >> 3, c4 = f & 7;
        aReg[i] = *(const float4*)(aBase + (size_t)row * DIM + (c4 << 2));
        bReg[i] = *(const float4*)(bBase + (size_t)row * DIM + (c4 << 2));
    }
#pragma unroll 1
    for (int s = 0; s < DIM / 32; ++s) {
#pragma unroll
        for (int i = 0; i < 4; ++i) {
            int f = tid + 256 * i;
            int row = f >> 3, c4 = f & 7;
            us4 av, bv;
            av.x = bf16rnd(aReg[i].x); av.y = bf16rnd(aReg[i].y);
            av.z = bf16rnd(aReg[i].z); av.w = bf16rnd(aReg[i].w);
            bv.x = bf16rnd(bReg[i].x); bv.y = bf16rnd(bReg[i].y);
            bv.z = bf16rnd(bReg[i].z); bv.w = bf16rnd(bReg[i].w);
            *(us4*)&As[row][c4 << 2] = av;
            *(us4*)&Bs[row][c4 << 2] = bv;
        }
        __syncthreads();
        if (s + 1 < DIM / 32) {
            int k0 = (s + 1) * 32;
#pragma unroll
            for (int i = 0; i < 4; ++i) {
                int f = tid + 256 * i;
                int row = f >> 3, c4 = f & 7;
                aReg[i] = *(const float4*)(aBase + (size_t)row * DIM + k0 + (c4 << 2));
                bReg[i] = *(const float4*)(bBase + (size_t)row * DIM + k0 + (c4 << 2));
            }
        }
        short8 aF[4], bF[4];
#pragma unroll
        for (int mi = 0; mi < 4; ++mi) aF[mi] = *(const short8*)&As[wr + mi * 16 + l15][q * 8];
#pragma unroll
        for (int ni = 0; ni < 4; ++ni) bF[ni] = *(const short8*)&Bs[wc + ni * 16 + l15][q * 8];
#pragma unroll
        for (int mi = 0; mi < 4; ++mi)
#pragma unroll
            for (int ni = 0; ni < 4; ++ni)
                acc[mi][ni] = __builtin_amdgcn_mfma_f32_16x16x32_bf16(aF[mi], bF[ni], acc[mi][ni], 0, 0, 0);
        __syncthreads();
    }

    const float scale = scale_p[0];
    float rsum[4][4];
    float csum[4] = {0.f, 0.f, 0.f, 0.f};
    float rl = 0.f;
#pragma unroll
    for (int mi = 0; mi < 4; ++mi)
#pragma unroll
        for (int r = 0; r < 4; ++r) rsum[mi][r] = 0.f;
#pragma unroll
    for (int mi = 0; mi < 4; ++mi) {
#pragma unroll
        for (int ni = 0; ni < 4; ++ni) {
#pragma unroll
            for (int r = 0; r < 4; ++r) {
                float sim = acc[mi][ni][r] * scale;
                float e = __expf(sim - SHIFT);
                rsum[mi][r] += e;
                csum[ni] += e;
                rl += fmaxf(sim, 0.f);
                int rg = rowBase + wr + mi * 16 + q * 4 + r;
                int cg = colBase + wc + ni * 16 + l15;
                if ((cg >> 3) == rg) pos_sim[cg] = sim;
            }
        }
    }
#pragma unroll
    for (int mi = 0; mi < 4; ++mi) {
#pragma unroll
        for (int r = 0; r < 4; ++r) {
            float v = rsum[mi][r];
            v += __shfl_xor(v, 1); v += __shfl_xor(v, 2);
            v += __shfl_xor(v, 4); v += __shfl_xor(v, 8);
            if (l15 == 0)
                atomicAdd(&row_se[rowBase + wr + mi * 16 + q * 4 + r], v);
        }
    }
#pragma unroll
    for (int ni = 0; ni < 4; ++ni) {
        float v = csum[ni];
        v += __shfl_xor(v, 16); v += __shfl_xor(v, 32);
        if (q == 0)
            atomicAdd(&col_se[colBase + wc + ni * 16 + l15], v);
    }
#pragma unroll
    for (int m = 1; m < 64; m <<= 1) rl += __shfl_xor(rl, m);
    if (lane == 0) redBuf[wave] = rl;
    __syncthreads();
    if (tid == 0)
        atomicAdd(&scalars[0], redBuf[0] + redBuf[1] + redBuf[2] + redBuf[3]);
}

// ---- finalize: 64 parallel blocks; last block (ticket) writes the output ----
__global__ __launch_bounds__(256)
void finalize_mb(const float* __restrict__ row_se, const float* __restrict__ col_se,
                 const float* __restrict__ pos_sim, const float* __restrict__ pic50,
                 float* __restrict__ scalars, float* __restrict__ out)
{
    int j = blockIdx.x * 256 + threadIdx.x;   // mol index
    float m2p = SHIFT + __logf(col_se[j]) - pos_sim[j];

    float p2m = 0.f, rank = 0.f, prelu = 0.f;
    if ((j & 7) == 0) {
        int i = j >> 3;
        float s[8], pc[8], pr[8];
#pragma unroll
        for (int p = 0; p < 8; ++p) {
            s[p]  = pos_sim[j + p];
            pr[p] = pic50[(size_t)i * N_MOLS + j + p];
            float x = (pr[p] - 2.0f) * 0.125f;
            pc[p] = fminf(fmaxf(x, 0.f), 1.f);
            prelu += fmaxf(s[p], 0.f);
        }
        float wsum = 1e-8f;
#pragma unroll
        for (int p = 0; p < 8; ++p) wsum += pc[p];
        float lse = SHIFT + __logf(row_se[i]);
        float accp = 0.f;
#pragma unroll
        for (int p = 0; p < 8; ++p) accp += pc[p] * (lse - s[p]);
        p2m = accp / wsum;
#pragma unroll
        for (int a = 0; a < 8; ++a)
#pragma unroll
            for (int b = a + 1; b < 8; ++b) {
                float dp = pr[a] - pr[b];
                float ds = s[a] - s[b];
                float v = (dp > 0.f) ? fmaxf(MARGIN - ds, 0.f)
                        : ((dp < 0.f) ? fmaxf(MARGIN + ds, 0.f) : 0.f);
                rank += v;
            }
    }

#pragma unroll
    for (int m = 1; m < 64; m <<= 1) {
        m2p   += __shfl_xor(m2p, m);
        p2m   += __shfl_xor(p2m, m);
        rank  += __shfl_xor(rank, m);
        prelu += __shfl_xor(prelu, m);
    }
    __shared__ float rbuf[4][4];
    const int wave = threadIdx.x >> 6, lane = threadIdx.x & 63;
    if (lane == 0) { rbuf[wave][0] = m2p; rbuf[wave][1] = p2m;
                     rbuf[wave][2] = rank; rbuf[wave][3] = prelu; }
    __syncthreads();
    if (threadIdx.x == 0) {
        float a = 0, b = 0, c = 0, d = 0;
        for (int w = 0; w < 4; ++w) { a += rbuf[w][0]; b += rbuf[w][1];
                                      c += rbuf[w][2]; d += rbuf[w][3]; }
        atomicAdd(&scalars[2], a);
        atomicAdd(&scalars[1], b);
        atomicAdd(&scalars[3], c);
        atomicAdd(&scalars[4], d);
        __threadfence();
        float old = atomicAdd(&scalars[7], 1.0f);   // ticket
        if (old == (float)(N_MOLS / 256 - 1)) {
            // all blocks done; read via atomic RMW for device-scope coherence
            float s0 = atomicAdd(&scalars[0], 0.0f);
            float s1 = atomicAdd(&scalars[1], 0.0f);
            float s2 = atomicAdd(&scalars[2], 0.0f);
            float s3 = atomicAdd(&scalars[3], 0.0f);
            float s4 = atomicAdd(&scalars[4], 0.0f);
            float relu_neg = s0 - s4;
            float p2mv  = s1 / (float)N_PROTS;
            float m2pv  = s2 / (float)N_MOLS;
            float rankv = s3 / ((float)N_PROTS * 28.0f);
            float negv  = relu_neg / ((float)N_PROTS * (float)N_MOLS);
            out[0] = p2mv + m2pv + 0.5f * rankv + 0.1f * negv;
            out[1] = p2mv;
            out[2] = m2pv;
            out[3] = rankv;
            out[4] = negv;
        }
    }
}

extern "C" void kernel_launch(void* const* d_in, const int* in_sizes, int n_in,
                              void* d_out, int out_size, void* d_ws, size_t ws_size,
                              hipStream_t stream) {
    const float* prot   = (const float*)d_in[0];
    const float* mol    = (const float*)d_in[1];
    const float* pic50  = (const float*)d_in[3];
    const float* lscale = (const float*)d_in[4];

    float* ws      = (float*)d_ws;
    float* row_se  = ws;
    float* col_se  = ws + 2048;
    float* pos_sim = ws + 2048 + 16384;
    float* scalars = ws + 2048 + 16384 + 16384;

    if (ws_size >= WS_NEED) {
        unsigned short* protBf = (unsigned short*)((char*)d_ws + PROT_BF_OFF_B);
        unsigned short* molBf  = (unsigned short*)((char*)d_ws + MOL_BF_OFF_B);
        size_t groups = ((size_t)N_PROTS + N_MOLS) * DIM / 8;   // 1,769,472
        convert_bf16<<<(unsigned)(groups / 256), 256, 0, stream>>>(prot, mol, protBf, molBf, ws);
        sim_pass_bf16_v4<<<512, 512, 0, stream>>>(protBf, molBf, lscale, row_se, col_se, pos_sim, scalars);
    } else {
        hipMemsetAsync(d_ws, 0, (size_t)ACC_FLOATS * sizeof(float), stream);
        dim3 grid(N_MOLS / 128, N_PROTS / 128);
        sim_pass<<<grid, 256, 0, stream>>>(prot, mol, lscale, row_se, col_se, pos_sim, scalars);
    }
    finalize_mb<<<N_MOLS / 256, 256, 0, stream>>>(row_se, col_se, pos_sim, pic50, scalars, (float*)d_out);
}